// Round 8
// baseline (289.987 us; speedup 1.0000x reference)
//
#include <hip/hip_runtime.h>
#include <hip/hip_bf16.h>

// Problem constants
#define B_ 128
#define S_ 128
#define H_ 512
#define R_ 16
#define IN_ 2
#define OPS_ 5
#define NPAD_ 16
#define L_ 18          // IN_ + NPAD_
#define NEGV (-1000000000000.0f)
#define C2_ (-2.885390081777927f)   // -2*log2(e):  tanh(x) = 2*rcp(1+exp2(C2*x)) - 1

typedef __bf16 bf16_t;
typedef bf16_t bf16x8 __attribute__((ext_vector_type(8)));
typedef float floatx4 __attribute__((ext_vector_type(4)));

__device__ __forceinline__ float rcp_f(float x) { return __builtin_amdgcn_rcpf(x); }
__device__ __forceinline__ float exp2_f(float x) { return __builtin_amdgcn_exp2f(x); }

__device__ __forceinline__ float fast_tanh(float x) {
    return 2.0f * rcp_f(1.0f + exp2_f(C2_ * x)) - 1.0f;
}
__device__ __forceinline__ float fast_sigmoid(float x) {
    return rcp_f(1.0f + exp2_f(-1.4426950408889634f * x));
}
__device__ __forceinline__ unsigned short f2bf(float f) {   // RNE
    unsigned int u = __builtin_bit_cast(unsigned int, f);
    u += 0x7fff + ((u >> 16) & 1);
    return (unsigned short)(u >> 16);
}
__device__ __forceinline__ float bf2f(unsigned short u) {
    return __builtin_bit_cast(float, (unsigned int)u << 16);
}

// async 16B global->LDS DMA (lds dest = wave-uniform base + lane*16)
__device__ __forceinline__ void glds16(const void* g, void* l) {
    __builtin_amdgcn_global_load_lds(
        (const __attribute__((address_space(1))) void*)g,
        (__attribute__((address_space(3))) void*)l, 16, 0, 0);
}

// ---------------------------------------------------------------------------
// bf16 MFMA tile body: one 128x128 C-tile at (m0,n0). A row-major [.,K],
// Bt row-major [N,K] (=B^T). global_load_lds staging, LDS double-buffered
// (1 barrier/iter). LDS rows unpadded (32 shorts) with XOR-16B-chunk swizzle:
//   writer lane i sources chunk (i&3)^((i>>3)&3); reader uses
//   chunk quad^((mn>>1)&3). Both equal key (destrow>>1)&3 -> <=2-way conflicts.
// Operand-SWAPPED mfma: lane holds row=lane&15, cols=quad*4+reg (contiguous).
// ---------------------------------------------------------------------------
#define LROW 32              // shorts per LDS row
#define LBUF 4096            // 128*32 shorts per buffer

__device__ __forceinline__ void mfma_tile(const unsigned short* __restrict__ A,
                                          const unsigned short* __restrict__ Bt,
                                          void* __restrict__ Cv, bool bf16_out,
                                          int m0, int n0, int K, int ldc,
                                          unsigned short* As, unsigned short* Bs) {
    const int tid  = threadIdx.x;
    const int w    = tid >> 6, lane = tid & 63;
    const int quad = lane >> 4, mn = lane & 15;
    const int wm = (w & 1) * 64, wn = (w >> 1) * 64;
    const int sr = tid >> 2;
    const int csw = ((tid & 3) ^ ((tid >> 3) & 3)) * 8;   // swizzled source chunk
    const int qs  = (quad ^ ((mn >> 1) & 3)) * 8;         // swizzled read offset

    const unsigned short* pa0 = A  + (size_t)(m0 + sr)      * K + csw;
    const unsigned short* pa1 = A  + (size_t)(m0 + sr + 64) * K + csw;
    const unsigned short* pb0 = Bt + (size_t)(n0 + sr)      * K + csw;
    const unsigned short* pb1 = Bt + (size_t)(n0 + sr + 64) * K + csw;

    const int wbase = w * 512;   // w*16 rows * 32 shorts
    glds16(pa0, As + wbase);
    glds16(pa1, As + wbase + 2048);
    glds16(pb0, Bs + wbase);
    glds16(pb1, Bs + wbase + 2048);
    __syncthreads();

    floatx4 acc[4][4] = {};

    for (int k0 = 0; k0 < K; k0 += 32) {
        const int cur = (k0 >> 5) & 1;
        const unsigned short* Asb = As + cur * LBUF;
        const unsigned short* Bsb = Bs + cur * LBUF;

        if (k0 + 32 < K) {
            const int nb = cur ^ 1;
            glds16(pa0 + k0 + 32, As + nb * LBUF + wbase);
            glds16(pa1 + k0 + 32, As + nb * LBUF + wbase + 2048);
            glds16(pb0 + k0 + 32, Bs + nb * LBUF + wbase);
            glds16(pb1 + k0 + 32, Bs + nb * LBUF + wbase + 2048);
        }

        bf16x8 af[4], bfr[4];
        #pragma unroll
        for (int i = 0; i < 4; ++i)
            af[i] = *(const bf16x8*)&Asb[(wm + i * 16 + mn) * LROW + qs];
        #pragma unroll
        for (int j = 0; j < 4; ++j)
            bfr[j] = *(const bf16x8*)&Bsb[(wn + j * 16 + mn) * LROW + qs];

        #pragma unroll
        for (int i = 0; i < 4; ++i)
            #pragma unroll
            for (int j = 0; j < 4; ++j)
                acc[i][j] = __builtin_amdgcn_mfma_f32_16x16x32_bf16(bfr[j], af[i], acc[i][j], 0, 0, 0);

        __syncthreads();   // drains prefetch DMA (vmcnt) + protects buffer swap
    }

    // C[row = m0+wm+i*16+mn][col = n0+wn+j*16+quad*4 + r], r contiguous
    #pragma unroll
    for (int i = 0; i < 4; ++i) {
        int row = m0 + wm + i * 16 + mn;
        #pragma unroll
        for (int j = 0; j < 4; ++j) {
            int col = n0 + wn + j * 16 + quad * 4;
            if (bf16_out) {
                ushort4 v = {f2bf(acc[i][j][0]), f2bf(acc[i][j][1]),
                             f2bf(acc[i][j][2]), f2bf(acc[i][j][3])};
                *(ushort4*)((unsigned short*)Cv + (size_t)row * ldc + col) = v;
            } else {
                float4 v = {acc[i][j][0], acc[i][j][1], acc[i][j][2], acc[i][j][3]};
                *(float4*)((float*)Cv + (size_t)row * ldc + col) = v;
            }
        }
    }
}

// mega-GEMM 1: blocks 0..1023 = EO_bf @ Wcat (N=1024 -> eobuf bf16, ld 1024),
//   XCD-friendly mapping m=blk&127, n=blk>>7; blocks 1024..1027 = q_bf @ T5.
__global__ __launch_bounds__(256) void k_gemm_mega1(const unsigned short* __restrict__ EO_bf,
                                                    const unsigned short* __restrict__ Wcat,
                                                    unsigned short* __restrict__ eobuf,
                                                    const unsigned short* __restrict__ q_bf,
                                                    const unsigned short* __restrict__ T5,
                                                    float* __restrict__ qT) {
    __shared__ unsigned short As[2 * LBUF];
    __shared__ unsigned short Bs[2 * LBUF];
    int blk = blockIdx.x;
    if (blk < 1024)
        mfma_tile(EO_bf, Wcat, eobuf, true, (blk & 127) * 128, (blk >> 7) * 128, 512, 1024, As, Bs);
    else
        mfma_tile(q_bf, T5, qT, false, 0, (blk - 1024) * 128, 512, 512, As, Bs);
}

// mega-GEMM 2: rctx@T8 (64 blk), leaf@T9 (4 blk), ew@T10 (72 blk)
__global__ __launch_bounds__(256) void k_gemm_mega2(const unsigned short* __restrict__ rctx_bf,
                                                    const unsigned short* __restrict__ T8,
                                                    float* __restrict__ rclin,
                                                    const unsigned short* __restrict__ leaf_bf,
                                                    const unsigned short* __restrict__ T9,
                                                    float* __restrict__ lsb,
                                                    const unsigned short* __restrict__ ew_bf,
                                                    const unsigned short* __restrict__ T10,
                                                    unsigned short* __restrict__ ewp_bf) {
    __shared__ unsigned short As[2 * LBUF];
    __shared__ unsigned short Bs[2 * LBUF];
    int blk = blockIdx.x;
    if (blk < 64)
        mfma_tile(rctx_bf, T8, rclin, false, (blk >> 2) * 128, (blk & 3) * 128, 512, 512, As, Bs);
    else if (blk < 68)
        mfma_tile(leaf_bf, T9, lsb, false, 0, (blk - 64) * 128, 1024, 512, As, Bs);
    else {
        int r = blk - 68;
        mfma_tile(ew_bf, T10, ewp_bf, true, (r >> 2) * 128, (r & 3) * 128, 512, 512, As, Bs);
    }
}

// z-batched 5-job GEMM, N=512 fixed, M<=128 (row-clamped loads, guarded stores)
struct MJ5 {
    const unsigned short* A[5]; const unsigned short* Bt[5]; float* C[5];
    int M[5]; int K[5];
};
__global__ __launch_bounds__(256) void gemm_bf16_j5(MJ5 g) {
    __shared__ unsigned short As[2 * LBUF];
    __shared__ unsigned short Bs[2 * LBUF];

    const int z = blockIdx.z;
    const unsigned short* A  = g.A[z];
    const unsigned short* Bt = g.Bt[z];
    float* C = g.C[z];
    const int M = g.M[z], K = g.K[z];

    const int tid  = threadIdx.x;
    const int w    = tid >> 6, lane = tid & 63;
    const int quad = lane >> 4, mn = lane & 15;
    const int wm = (w & 1) * 64, wn = (w >> 1) * 64;
    const int n0 = blockIdx.x * 128;

    const int sr = tid >> 2;
    const int csw = ((tid & 3) ^ ((tid >> 3) & 3)) * 8;
    const int qs  = (quad ^ ((mn >> 1) & 3)) * 8;
    const int ra0 = min(sr, M - 1);
    const int ra1 = min(sr + 64, M - 1);

    const unsigned short* pa0 = A  + (size_t)ra0 * K + csw;
    const unsigned short* pa1 = A  + (size_t)ra1 * K + csw;
    const unsigned short* pb0 = Bt + (size_t)(n0 + sr)      * K + csw;
    const unsigned short* pb1 = Bt + (size_t)(n0 + sr + 64) * K + csw;

    const int wbase = w * 512;
    glds16(pa0, As + wbase);
    glds16(pa1, As + wbase + 2048);
    glds16(pb0, Bs + wbase);
    glds16(pb1, Bs + wbase + 2048);
    __syncthreads();

    floatx4 acc[4][4] = {};

    for (int k0 = 0; k0 < K; k0 += 32) {
        const int cur = (k0 >> 5) & 1;
        const unsigned short* Asb = As + cur * LBUF;
        const unsigned short* Bsb = Bs + cur * LBUF;

        if (k0 + 32 < K) {
            const int nb = cur ^ 1;
            glds16(pa0 + k0 + 32, As + nb * LBUF + wbase);
            glds16(pa1 + k0 + 32, As + nb * LBUF + wbase + 2048);
            glds16(pb0 + k0 + 32, Bs + nb * LBUF + wbase);
            glds16(pb1 + k0 + 32, Bs + nb * LBUF + wbase + 2048);
        }

        bf16x8 af[4], bfr[4];
        #pragma unroll
        for (int i = 0; i < 4; ++i)
            af[i] = *(const bf16x8*)&Asb[(wm + i * 16 + mn) * LROW + qs];
        #pragma unroll
        for (int j = 0; j < 4; ++j)
            bfr[j] = *(const bf16x8*)&Bsb[(wn + j * 16 + mn) * LROW + qs];

        #pragma unroll
        for (int i = 0; i < 4; ++i)
            #pragma unroll
            for (int j = 0; j < 4; ++j)
                acc[i][j] = __builtin_amdgcn_mfma_f32_16x16x32_bf16(bfr[j], af[i], acc[i][j], 0, 0, 0);

        __syncthreads();
    }

    #pragma unroll
    for (int i = 0; i < 4; ++i) {
        int row = wm + i * 16 + mn;
        if (row < M) {
            #pragma unroll
            for (int j = 0; j < 4; ++j) {
                int col = n0 + wn + j * 16 + quad * 4;
                float4 v = {acc[i][j][0], acc[i][j][1], acc[i][j][2], acc[i][j][3]};
                *(float4*)(C + (size_t)row * 512 + col) = v;
            }
        }
    }
}

// ---------------------------------------------------------------------------
// fused prep: EO cast | ew build | c/acat/rsc cast | 11 weight transposes
// ---------------------------------------------------------------------------
struct PrepArgs {
    const float *EO, *cur, *padh, *left, *rsc, *embw, *npad;
    const int* se;
    unsigned short *EO_bf, *c_bf, *acat_bf, *rsc_bf, *ew_bf;
    float* ew_out;
    const float* tsrc[11];
    unsigned short* tdst[11];
    int tK[11];
    int tbase[12];
};
#define PG_CAST 8192
#define PG_EW   1152
#define PG_PREP 288
#define PG_WT   3584
#define PG_TOTAL (PG_CAST + PG_EW + PG_PREP + PG_WT)   // 13216

__global__ __launch_bounds__(256) void k_prep_mega(PrepArgs a) {
    __shared__ float t[32][33];
    int blk = blockIdx.x, tid = threadIdx.x;
    if (blk < PG_CAST) {
        int i = (blk * 256 + tid) * 4;
        float4 v = *(const float4*)(a.EO + i);
        ushort4 o;
        o.x = f2bf(v.x); o.y = f2bf(v.y); o.z = f2bf(v.z); o.w = f2bf(v.w);
        *(ushort4*)(a.EO_bf + i) = o;
    } else if (blk < PG_CAST + PG_EW) {
        int i = ((blk - PG_CAST) * 256 + tid) * 4;
        int j = i & 511;
        int bl = i >> 9;
        int l = bl % L_;
        int b = bl / L_;
        const float* src = (l < IN_) ? (a.embw + l * H_ + j)
                                     : (a.npad + ((size_t)b * NPAD_ + (l - IN_)) * H_ + j);
        float4 v = *(const float4*)src;
        *(float4*)(a.ew_out + i) = v;
        ushort4 o;
        o.x = f2bf(v.x); o.y = f2bf(v.y); o.z = f2bf(v.z); o.w = f2bf(v.w);
        *(ushort4*)(a.ew_bf + i) = o;
    } else if (blk < PG_CAST + PG_EW + PG_PREP) {
        int i = (blk - PG_CAST - PG_EW) * 256 + tid;
        if (i < B_ * H_) {
            int b = i >> 9, j = i & 511;
            float cv = a.se[b] ? a.padh[j] : a.cur[i];
            a.c_bf[i] = f2bf(cv);
            a.acat_bf[b * 1024 + j] = f2bf(a.left[i]);
            a.acat_bf[b * 1024 + 512 + j] = f2bf(cv);
        } else {
            int k = i - B_ * H_;
            a.rsc_bf[k] = f2bf(a.rsc[k]);
        }
    } else {
        int rel = blk - (PG_CAST + PG_EW + PG_PREP);
        int j = 0;
        while (rel >= a.tbase[j + 1]) ++j;
        int r = rel - a.tbase[j];
        int K = a.tK[j];
        const float* src = a.tsrc[j];
        unsigned short* dst = a.tdst[j];
        int bx = (r & 15) * 32;   // n tile
        int by = (r >> 4) * 32;   // k tile
        int tx = tid & 31, ty = tid >> 5;
        #pragma unroll
        for (int i = 0; i < 32; i += 8)
            t[ty + i][tx] = src[(size_t)(by + ty + i) * 512 + bx + tx];
        __syncthreads();
        #pragma unroll
        for (int i = 0; i < 32; i += 8)
            dst[(size_t)(bx + ty + i) * K + by + tx] = f2bf(t[tx][ty + i]);
    }
}

// gates -> q_bf, node_out (fp32 output), leaf_bf[:, :H]
__global__ void k_node(const float* __restrict__ gl, const float* __restrict__ glg,
                       const float* __restrict__ gr, const float* __restrict__ grg,
                       const float* __restrict__ bl, const float* __restrict__ blg,
                       const float* __restrict__ br, const float* __restrict__ brg,
                       const int* __restrict__ hl,
                       unsigned short* __restrict__ q_bf, float* __restrict__ node_out,
                       unsigned short* __restrict__ leaf_bf) {
    int i = blockIdx.x * blockDim.x + threadIdx.x;
    int b = i >> 9, j = i & 511;
    float nl = fast_tanh(gl[i] + bl[j]) * fast_sigmoid(glg[i] + blg[j]);
    float nr = fast_tanh(gr[i] + br[j]) * fast_sigmoid(grg[i] + brg[j]);
    float v = hl[b] ? nr : nl;
    node_out[i] = v;
    q_bf[i] = f2bf(v);
    leaf_bf[b * 1024 + j] = f2bf(v);
}

// ---------------------------------------------------------------------------
// fused scores: blocks 0..127 = tree score+softmax (block per b);
//               blocks 128..4223 = rule scores (wave per (s,b)-row)
// eobuf stride 1024: cols 0..511 tree proj, 512..1023 rule proj
// ---------------------------------------------------------------------------
__global__ __launch_bounds__(256) void k_score_fused(const float* __restrict__ qT,
                                                     const unsigned short* __restrict__ eobuf,
                                                     const float* __restrict__ b_ta,
                                                     const float* __restrict__ w_ts,
                                                     const float* __restrict__ b_ts,
                                                     const float* __restrict__ RP,
                                                     const float* __restrict__ b_ra,
                                                     const float* __restrict__ w_rs,
                                                     const float* __restrict__ b_rs,
                                                     const int* __restrict__ sm,
                                                     float* __restrict__ attn,
                                                     float* __restrict__ comb) {
    __shared__ float sc[S_];
    int blk = blockIdx.x;
    int tid = threadIdx.x;
    int wid = tid >> 6, lane = tid & 63;
    int j0 = lane * 8;

    if (blk < 128) {
        // ---- tree score + softmax ----
        int b = blk;
        float4 q0 = *(const float4*)(qT + b * H_ + j0);
        float4 q1 = *(const float4*)(qT + b * H_ + j0 + 4);
        float4 t0 = *(const float4*)(b_ta + j0);
        float4 t1 = *(const float4*)(b_ta + j0 + 4);
        float4 w0 = *(const float4*)(w_ts + j0);
        float4 w1 = *(const float4*)(w_ts + j0 + 4);
        float qc[8] = {C2_*(q0.x+t0.x), C2_*(q0.y+t0.y), C2_*(q0.z+t0.z), C2_*(q0.w+t0.w),
                       C2_*(q1.x+t1.x), C2_*(q1.y+t1.y), C2_*(q1.z+t1.z), C2_*(q1.w+t1.w)};
        float w2[8] = {2*w0.x, 2*w0.y, 2*w0.z, 2*w0.w, 2*w1.x, 2*w1.y, 2*w1.z, 2*w1.w};
        float wsum = 0.5f * (w2[0]+w2[1]+w2[2]+w2[3]+w2[4]+w2[5]+w2[6]+w2[7]);
        float bias = b_ts[0];

        for (int s = wid; s < S_; s += 4) {
            if (sm[b * S_ + s]) {
                if (lane == 0) sc[s] = NEGV;
                continue;
            }
            uint4 ev = *(const uint4*)(eobuf + ((size_t)s * B_ + b) * 1024 + j0);
            const unsigned short* ep = (const unsigned short*)&ev;
            float acc = -wsum;
            #pragma unroll
            for (int k = 0; k < 8; ++k) {
                float y = fmaf(C2_, bf2f(ep[k]), qc[k]);
                acc = fmaf(w2[k], rcp_f(1.0f + exp2_f(y)), acc);
            }
            #pragma unroll
            for (int o = 32; o > 0; o >>= 1) acc += __shfl_xor(acc, o);
            if (lane == 0) sc[s] = acc + bias;
        }
        __syncthreads();
        if (tid < 64) {
            float v0 = sc[tid], v1 = sc[tid + 64];
            float m = fmaxf(v0, v1);
            #pragma unroll
            for (int o = 32; o > 0; o >>= 1) m = fmaxf(m, __shfl_xor(m, o));
            float e0 = __expf(v0 - m), e1 = __expf(v1 - m);
            float ss = e0 + e1;
            #pragma unroll
            for (int o = 32; o > 0; o >>= 1) ss += __shfl_xor(ss, o);
            float r = rcp_f(ss);
            attn[b * S_ + tid] = e0 * r;
            attn[b * S_ + tid + 64] = e1 * r;
        }
        return;
    }

    // ---- rule scores ----
    int row = (blk - 128) * 4 + wid;   // s*B + b
    int s = row >> 7, b = row & 127;
    bool masked = sm[b * S_ + s] != 0;
    if (masked) {
        if (lane < R_) comb[((size_t)b * R_ + lane) * S_ + s] = NEGV;
        return;
    }
    uint4 ev = *(const uint4*)(eobuf + (size_t)row * 1024 + 512 + j0);
    const unsigned short* ep = (const unsigned short*)&ev;
    float4 a0 = *(const float4*)(b_ra + j0);
    float4 a1 = *(const float4*)(b_ra + j0 + 4);
    float4 w0 = *(const float4*)(w_rs + j0);
    float4 w1 = *(const float4*)(w_rs + j0 + 4);
    float ba[8] = {a0.x, a0.y, a0.z, a0.w, a1.x, a1.y, a1.z, a1.w};
    float w2[8], ed[8];
    float wsum = 0.f;
    {
        float w[8] = {w0.x, w0.y, w0.z, w0.w, w1.x, w1.y, w1.z, w1.w};
        #pragma unroll
        for (int k = 0; k < 8; ++k) {
            wsum += w[k];
            w2[k] = 2.0f * w[k];
            ed[k] = C2_ * (bf2f(ep[k]) + ba[k]);
        }
    }
    float bias = b_rs[0];
    #pragma unroll
    for (int r = 0; r < R_; ++r) {
        float4 r0 = *(const float4*)(RP + r * H_ + j0);
        float4 r1 = *(const float4*)(RP + r * H_ + j0 + 4);
        float rp[8] = {r0.x, r0.y, r0.z, r0.w, r1.x, r1.y, r1.z, r1.w};
        float acc = -wsum;
        #pragma unroll
        for (int k = 0; k < 8; ++k) {
            float y = fmaf(C2_, rp[k], ed[k]);
            acc = fmaf(w2[k], rcp_f(1.0f + exp2_f(y)), acc);
        }
        #pragma unroll
        for (int o = 32; o > 0; o >>= 1) acc += __shfl_xor(acc, o);
        if (lane == 0) comb[((size_t)b * R_ + r) * S_ + s] = acc + bias;
    }
}

// ---------------------------------------------------------------------------
// fused rules-softmax + contexts: grid (b, jhalf), 256 threads.
// comb (RAW rule scores) read from GLOBAL for softmax; result stored in LDS
// as [s][r] with stride 20 (16B-aligned float4 rows, broadcast-friendly).
// Context loop: 4 ds_read_b128 (broadcast) + 16 fma per (thread, s).
// ---------------------------------------------------------------------------
__global__ __launch_bounds__(256) void k_ctxsm(const unsigned short* __restrict__ EO_bf,
                                               const float* __restrict__ attn,
                                               const float* __restrict__ comb,
                                               const int* __restrict__ sm,
                                               float* __restrict__ ctx_out,
                                               unsigned short* __restrict__ leaf_bf,
                                               unsigned short* __restrict__ rctx) {
    __shared__ float cb2[S_ * 20];   // [s][r] padded to 20
    __shared__ float at[S_];
    __shared__ short usl[S_];
    __shared__ int ucount;
    int b = blockIdx.x;
    int tid = threadIdx.x;
    int w = tid >> 6, lane = tid & 63;

    if (tid < S_) at[tid] = attn[b * S_ + tid];
    if (tid == 0) {
        int c = 0;
        for (int s = 0; s < S_; ++s)
            if (!sm[b * S_ + s]) usl[c++] = (short)s;
        ucount = c;
    }
    __syncthreads();

    // softmax over s: 4 waves x 4 rows = 16; input from global comb
    #pragma unroll
    for (int rr = 0; rr < 4; ++rr) {
        int r = w * 4 + rr;
        const float* rowp = comb + (size_t)b * R_ * S_ + r * S_;
        float v0 = rowp[lane], v1 = rowp[lane + 64];
        float m = fmaxf(v0, v1);
        #pragma unroll
        for (int o = 32; o > 0; o >>= 1) m = fmaxf(m, __shfl_xor(m, o));
        float e0 = __expf(v0 - m), e1 = __expf(v1 - m);
        float ss = e0 + e1;
        #pragma unroll
        for (int o = 32; o > 0; o >>= 1) ss += __shfl_xor(ss, o);
        float rc_ = rcp_f(ss);
        cb2[lane * 20 + r]        = e0 * rc_ + 0.2f * at[lane];
        cb2[(lane + 64) * 20 + r] = e1 * rc_ + 0.2f * at[lane + 64];
    }
    __syncthreads();

    int j = blockIdx.y * 256 + tid;
    int nu = ucount;
    float ctx = 0.f;
    float rc[R_] = {};
    for (int ii = 0; ii < nu; ++ii) {
        int s = usl[ii];
        float eo = bf2f(EO_bf[((size_t)s * B_ + b) * H_ + j]);
        float4 c0 = *(const float4*)&cb2[s * 20];
        float4 c1 = *(const float4*)&cb2[s * 20 + 4];
        float4 c2 = *(const float4*)&cb2[s * 20 + 8];
        float4 c3 = *(const float4*)&cb2[s * 20 + 12];
        ctx = fmaf(at[s], eo, ctx);
        rc[0]  = fmaf(c0.x, eo, rc[0]);  rc[1]  = fmaf(c0.y, eo, rc[1]);
        rc[2]  = fmaf(c0.z, eo, rc[2]);  rc[3]  = fmaf(c0.w, eo, rc[3]);
        rc[4]  = fmaf(c1.x, eo, rc[4]);  rc[5]  = fmaf(c1.y, eo, rc[5]);
        rc[6]  = fmaf(c1.z, eo, rc[6]);  rc[7]  = fmaf(c1.w, eo, rc[7]);
        rc[8]  = fmaf(c2.x, eo, rc[8]);  rc[9]  = fmaf(c2.y, eo, rc[9]);
        rc[10] = fmaf(c2.z, eo, rc[10]); rc[11] = fmaf(c2.w, eo, rc[11]);
        rc[12] = fmaf(c3.x, eo, rc[12]); rc[13] = fmaf(c3.y, eo, rc[13]);
        rc[14] = fmaf(c3.z, eo, rc[14]); rc[15] = fmaf(c3.w, eo, rc[15]);
    }
    ctx_out[b * H_ + j] = ctx;
    leaf_bf[b * 1024 + 512 + j] = f2bf(ctx);
    #pragma unroll
    for (int r = 0; r < R_; ++r) rctx[((size_t)b * R_ + r) * H_ + j] = f2bf(rc[r]);
}

// ---------------------------------------------------------------------------
// fused epilogue: rp2 (blocks 0..127) | numscore (128..703) | op (704..735)
// ---------------------------------------------------------------------------
__global__ __launch_bounds__(256) void k_epilogue(const float* __restrict__ rclin,
                                                  const float* __restrict__ b_rp1,
                                                  const float* __restrict__ w_rp2,
                                                  const float* __restrict__ b_rp2,
                                                  float* __restrict__ prob,
                                                  const float* __restrict__ lsb,
                                                  const unsigned short* __restrict__ ewp,
                                                  const float* __restrict__ b_sc,
                                                  const float* __restrict__ w_scs,
                                                  const int* __restrict__ mask_nums,
                                                  float* __restrict__ ns_out,
                                                  const unsigned short* __restrict__ leaf_bf,
                                                  const float* __restrict__ Wops,
                                                  const float* __restrict__ bops,
                                                  float* __restrict__ op_out) {
    __shared__ float sc[R_];
    int blk = blockIdx.x;
    int wid = threadIdx.x >> 6, lane = threadIdx.x & 63;
    if (blk < 128) {
        // ---- rule_prob ----
        int b = blk;
        int j0 = lane * 8;
        float4 p0 = *(const float4*)(b_rp1 + j0);
        float4 p1 = *(const float4*)(b_rp1 + j0 + 4);
        float4 w0 = *(const float4*)(w_rp2 + j0);
        float4 w1 = *(const float4*)(w_rp2 + j0 + 4);
        float brc[8] = {C2_*p0.x, C2_*p0.y, C2_*p0.z, C2_*p0.w,
                        C2_*p1.x, C2_*p1.y, C2_*p1.z, C2_*p1.w};
        float w[8] = {w0.x, w0.y, w0.z, w0.w, w1.x, w1.y, w1.z, w1.w};
        float wsum = 0.f;
        #pragma unroll
        for (int k = 0; k < 8; ++k) wsum += w[k];
        #pragma unroll
        for (int rr = 0; rr < 4; ++rr) {
            int r = wid * 4 + rr;
            const float* rl = rclin + ((size_t)b * R_ + r) * H_ + j0;
            float4 r0 = *(const float4*)(rl);
            float4 r1 = *(const float4*)(rl + 4);
            float rv[8] = {r0.x, r0.y, r0.z, r0.w, r1.x, r1.y, r1.z, r1.w};
            float acc = -wsum;
            #pragma unroll
            for (int k = 0; k < 8; ++k) {
                float y = fmaf(C2_, rv[k], brc[k]);
                acc = fmaf(2.0f * w[k], rcp_f(1.0f + exp2_f(y)), acc);
            }
            #pragma unroll
            for (int o = 32; o > 0; o >>= 1) acc += __shfl_xor(acc, o);
            if (lane == 0) sc[r] = acc + b_rp2[0];
        }
        __syncthreads();
        if (threadIdx.x < R_) {
            float m = -1e30f;
            for (int r = 0; r < R_; ++r) m = fmaxf(m, sc[r]);
            float sum = 0.f;
            for (int r = 0; r < R_; ++r) sum += __expf(sc[r] - m);
            prob[b * R_ + threadIdx.x] = __expf(sc[threadIdx.x] - m) * rcp_f(sum);
        }
    } else if (blk < 704) {
        // ---- num_score ----
        int row = (blk - 128) * 4 + wid;   // b*L + l, < 2304
        int b = row / L_, l = row - b * L_;
        bool masked = mask_nums[b * L_ + l] != 0;
        if (masked) {
            if (lane == 0) ns_out[b * L_ + l] = NEGV;
            return;
        }
        int j0 = lane * 8;
        uint4 ev = *(const uint4*)(ewp + (size_t)row * H_ + j0);
        const unsigned short* ep = (const unsigned short*)&ev;
        float4 l0 = *(const float4*)(lsb + b * H_ + j0);
        float4 l1 = *(const float4*)(lsb + b * H_ + j0 + 4);
        float4 s0 = *(const float4*)(b_sc + j0);
        float4 s1 = *(const float4*)(b_sc + j0 + 4);
        float4 w0 = *(const float4*)(w_scs + j0);
        float4 w1 = *(const float4*)(w_scs + j0 + 4);
        float lc[8] = {C2_*(l0.x+s0.x), C2_*(l0.y+s0.y), C2_*(l0.z+s0.z), C2_*(l0.w+s0.w),
                       C2_*(l1.x+s1.x), C2_*(l1.y+s1.y), C2_*(l1.z+s1.z), C2_*(l1.w+s1.w)};
        float w[8] = {w0.x, w0.y, w0.z, w0.w, w1.x, w1.y, w1.z, w1.w};
        float wsum = 0.f;
        #pragma unroll
        for (int k = 0; k < 8; ++k) wsum += w[k];
        float acc = -wsum;
        #pragma unroll
        for (int k = 0; k < 8; ++k) {
            float y = fmaf(C2_, bf2f(ep[k]), lc[k]);
            acc = fmaf(2.0f * w[k], rcp_f(1.0f + exp2_f(y)), acc);
        }
        #pragma unroll
        for (int o = 32; o > 0; o >>= 1) acc += __shfl_xor(acc, o);
        if (lane == 0) ns_out[b * L_ + l] = acc;
    } else {
        // ---- op ----  wave per b, 5 dots of K=1024
        int b = (blk - 704) * 4 + wid;
        int base = b * 1024 + lane * 16;
        uint4 v0 = *(const uint4*)(leaf_bf + base);
        uint4 v1 = *(const uint4*)(leaf_bf + base + 8);
        const unsigned short* lp0 = (const unsigned short*)&v0;
        const unsigned short* lp1 = (const unsigned short*)&v1;
        float lv[16];
        #pragma unroll
        for (int k = 0; k < 8; ++k) { lv[k] = bf2f(lp0[k]); lv[8 + k] = bf2f(lp1[k]); }
        #pragma unroll
        for (int o = 0; o < OPS_; ++o) {
            float acc = 0.f;
            #pragma unroll
            for (int k = 0; k < 16; ++k)
                acc = fmaf(lv[k], Wops[(size_t)(lane * 16 + k) * OPS_ + o], acc);
            #pragma unroll
            for (int of = 32; of > 0; of >>= 1) acc += __shfl_xor(acc, of);
            if (lane == 0) op_out[b * OPS_ + o] = acc + bops[o];
        }
    }
}

// ---------------------------------------------------------------------------
extern "C" void kernel_launch(void* const* d_in, const int* in_sizes, int n_in,
                              void* d_out, int out_size, void* d_ws, size_t ws_size,
                              hipStream_t stream) {
    const float* EO   = (const float*)d_in[0];
    const float* cur  = (const float*)d_in[1];
    const float* left = (const float*)d_in[2];
    const float* padh = (const float*)d_in[3];
    const float* npad = (const float*)d_in[4];
    const float* rsc  = (const float*)d_in[5];
    const float* embw = (const float*)d_in[6];
    const float* Wl   = (const float*)d_in[7];  const float* bl   = (const float*)d_in[8];
    const float* Wlg  = (const float*)d_in[9];  const float* blg  = (const float*)d_in[10];
    const float* Wr   = (const float*)d_in[11]; const float* br   = (const float*)d_in[12];
    const float* Wrg  = (const float*)d_in[13]; const float* brg  = (const float*)d_in[14];
    const float* Wta  = (const float*)d_in[15]; const float* bta  = (const float*)d_in[16];
    const float* Wts  = (const float*)d_in[17]; const float* bts  = (const float*)d_in[18];
    const float* Wra  = (const float*)d_in[19]; const float* bra  = (const float*)d_in[20];
    const float* Wrs  = (const float*)d_in[21]; const float* brs  = (const float*)d_in[22];
    const float* Wrp1 = (const float*)d_in[23]; const float* brp1 = (const float*)d_in[24];
    const float* Wrp2 = (const float*)d_in[25]; const float* brp2 = (const float*)d_in[26];
    const float* Wsa  = (const float*)d_in[27]; const float* bsa  = (const float*)d_in[28];
    const float* Wss  = (const float*)d_in[29];
    const float* Wops = (const float*)d_in[30]; const float* bops = (const float*)d_in[31];
    const int* smk = (const int*)d_in[32];
    const int* nmk = (const int*)d_in[33];
    const int* hlk = (const int*)d_in[34];
    const int* sek = (const int*)d_in[35];

    float* out = (float*)d_out;

    const size_t O_NS    = 0;
    const size_t O_OP    = O_NS + (size_t)B_ * L_;
    const size_t O_NODE  = O_OP + (size_t)B_ * OPS_;
    const size_t O_CTX   = O_NODE + (size_t)B_ * H_;
    const size_t O_EW    = O_CTX + (size_t)B_ * H_;
    const size_t O_RPROB = O_EW + (size_t)B_ * L_ * H_;

    // ---- workspace layout (no aliasing) ----
    float* f = (float*)d_ws;
    float* rp_buf = f;               f += 8192;      // R x H rule projection
    float* qT     = f;               f += 65536;
    float* attn   = f;               f += 16384;
    float* comb   = f;               f += 262144;
    float* gl     = f;               f += 65536;
    float* glg    = f;               f += 65536;
    float* gr     = f;               f += 65536;
    float* grg    = f;               f += 65536;
    float* lsb    = f;               f += 65536;
    float* rclin  = f;               f += 1048576;
    unsigned short* u = (unsigned short*)f;
    unsigned short* EO_bf   = u;     u += 8388608;
    unsigned short* ew_bf   = u;     u += 1179648;
    unsigned short* leaf_bf = u;     u += 131072;
    unsigned short* rctx_bf = u;     u += 1048576;
    unsigned short* Wcat    = u;     u += 524288;    // [Wta[h:]^T ; Wra[:h]^T]  1024x512
    unsigned short* T0      = u;     u += 262144;    // Wl^T
    unsigned short* T1      = u;     u += 262144;    // Wlg^T
    unsigned short* T2      = u;     u += 524288;    // Wr^T      K=1024
    unsigned short* T3      = u;     u += 524288;    // Wrg^T     K=1024
    unsigned short* T4      = u;     u += 262144;    // Wra[h:]^T
    unsigned short* T5      = u;     u += 262144;    // Wta[:h]^T
    unsigned short* T8      = u;     u += 262144;    // Wrp1^T
    unsigned short* T9      = u;     u += 524288;    // Wsa[:2h]^T K=1024
    unsigned short* T10     = u;     u += 262144;    // Wsa[2h:]^T
    unsigned short* q_bf    = u;     u += 65536;
    unsigned short* c_bf    = u;     u += 65536;
    unsigned short* acat_bf = u;     u += 131072;
    unsigned short* rsc_bf  = u;     u += 8192;
    unsigned short* ewp_bf  = u;     u += 1179648;
    unsigned short* eobuf   = u;     u += 16777216;  // 16384 x 1024

    // d1: fused prep
    PrepArgs a;
    a.EO = EO; a.cur = cur; a.padh = padh; a.left = left; a.rsc = rsc;
    a.embw = embw; a.npad = npad; a.se = sek;
    a.EO_bf = EO_bf; a.c_bf = c_bf; a.acat_bf = acat_bf; a.rsc_bf = rsc_bf;
    a.ew_bf = ew_bf; a.ew_out = out + O_EW;
    const float* tsrc[11] = {Wl, Wlg, Wr, Wrg, Wra + (size_t)H_ * H_, Wta,
                             Wta + (size_t)H_ * H_, Wra, Wrp1, Wsa, Wsa + (size_t)2 * H_ * H_};
    unsigned short* tdst[11] = {T0, T1, T2, T3, T4, T5, Wcat, Wcat + 512 * 512, T8, T9, T10};
    int tk[11] = {512, 512, 1024, 1024, 512, 512, 512, 512, 512, 1024, 512};
    int base = 0;
    for (int i = 0; i < 11; ++i) {
        a.tsrc[i] = tsrc[i]; a.tdst[i] = tdst[i]; a.tK[i] = tk[i];
        a.tbase[i] = base;
        base += 16 * (tk[i] / 32);
    }
    a.tbase[11] = base;   // 3584
    k_prep_mega<<<PG_TOTAL, 256, 0, stream>>>(a);

    // d2: 5-way batched MFMA (node gates + rule projection)
    MJ5 g;
    g.A[0] = c_bf;    g.Bt[0] = T0; g.C[0] = gl;     g.M[0] = B_;  g.K[0] = 512;
    g.A[1] = c_bf;    g.Bt[1] = T1; g.C[1] = glg;    g.M[1] = B_;  g.K[1] = 512;
    g.A[2] = acat_bf; g.Bt[2] = T2; g.C[2] = gr;     g.M[2] = B_;  g.K[2] = 1024;
    g.A[3] = acat_bf; g.Bt[3] = T3; g.C[3] = grg;    g.M[3] = B_;  g.K[3] = 1024;
    g.A[4] = rsc_bf;  g.Bt[4] = T4; g.C[4] = rp_buf; g.M[4] = R_;  g.K[4] = 512;
    gemm_bf16_j5<<<dim3(4, 1, 5), 256, 0, stream>>>(g);

    // d3: node gates
    k_node<<<256, 256, 0, stream>>>(gl, glg, gr, grg, bl, blg, br, brg, hlk,
                                    q_bf, out + O_NODE, leaf_bf);

    // d4: mega-GEMM 1 (EO projections fused N=1024, XCD-swizzled, + qT)
    k_gemm_mega1<<<1028, 256, 0, stream>>>(EO_bf, Wcat, eobuf, q_bf, T5, qT);

    // d5: fused scores (tree attn+softmax | rule scores)
    k_score_fused<<<128 + S_ * B_ / 4, 256, 0, stream>>>(
        qT, eobuf, bta, Wts, bts, rp_buf, bra, Wrs, brs, smk, attn, comb);

    // d6: fused rules-softmax + contexts
    k_ctxsm<<<dim3(B_, 2), 256, 0, stream>>>(EO_bf, attn, comb, smk, out + O_CTX,
                                             leaf_bf, rctx_bf);

    // d7: mega-GEMM 2 (rclin, lsb, ewp)
    k_gemm_mega2<<<140, 256, 0, stream>>>(rctx_bf, T8, rclin, leaf_bf, T9, lsb,
                                          ew_bf, T10, ewp_bf);

    // d8: fused epilogue (rule_prob, num_score, op)
    k_epilogue<<<736, 256, 0, stream>>>(rclin, brp1, Wrp2, brp2, out + O_RPROB,
                                        lsb, ewp_bf, bsa, Wss, nmk, out + O_NS,
                                        leaf_bf, Wops, bops, out + O_OP);
}